// Round 2
// baseline (206.798 us; speedup 1.0000x reference)
//
#include <hip/hip_runtime.h>
#include <hip/hip_bf16.h>

// Problem constants (reference: B=32, M=2048, E=128, 5 features)
constexpr int B = 32;
constexpr int M = 2048;
constexpr int E = 128;
constexpr int K = 5;
constexpr int PAIRS = B * M;              // 65536 output "pairs" (m,b)
constexpr int F4_PER_PAIR = E * K / 4;    // 640 floats = 160 float4 per pair

constexpr int BLOCK = 320;                // 5 waves; 2 pairs per block-iteration
constexpr int GRID  = 2048;               // pair stride = GRID*2 = 4096 (multiple of B)
constexpr int ITERS = PAIRS / (GRID * 2); // 16

// out flat layout (from torch view-scramble): ((m*B + b)*E + e)*5 + k
//   pair p = m*B + b  ->  b = p & 31, m = p >> 5
//   value = x[(b*M + m)*5 + k] * w_k[e] + b_k[e] + order_emb[k*E + e]
__global__ __launch_bounds__(BLOCK) void fuse_scramble_kernel(
    const float* __restrict__ x,
    const float* __restrict__ w_bet,  const float* __restrict__ b_bet,
    const float* __restrict__ w_stack,const float* __restrict__ b_stack,
    const float* __restrict__ w_call, const float* __restrict__ b_call,
    const float* __restrict__ w_odds, const float* __restrict__ b_odds,
    const float* __restrict__ oe,
    float* __restrict__ out)
{
    const int tid  = threadIdx.x;
    const int q    = tid % F4_PER_PAIR;   // float4 slot within a pair
    const int half = tid / F4_PER_PAIR;   // which of the block's 2 pairs

    // Per-thread constants: the 4 (w, add) values + x-row k-offsets for this slot.
    float w4[4], a4[4];
    int   kk[4];
#pragma unroll
    for (int j = 0; j < 4; ++j) {
        const int idx = 4 * q + j;        // 0..639
        const int e   = idx / 5;
        const int k   = idx - 5 * e;
        kk[j] = k;
        const float* wp = (k == 0) ? w_bet : (k <= 2) ? w_stack : (k == 3) ? w_call : w_odds;
        const float* bp = (k == 0) ? b_bet : (k <= 2) ? b_stack : (k == 3) ? b_call : b_odds;
        w4[j] = wp[e];
        a4[j] = bp[e] + oe[k * E + e];
    }

    // First pair for this thread; stride 4096 keeps b fixed, m += 128.
    const int p0 = blockIdx.x * 2 + half;
    const int b  = p0 & (B - 1);
    const int m0 = p0 >> 5;

    const float* xr = x + ((size_t)b * M + m0) * K;          // +=  128*5 floats per iter
    float4* op = reinterpret_cast<float4*>(out) + (size_t)p0 * F4_PER_PAIR + q;

#pragma unroll 2
    for (int it = 0; it < ITERS; ++it) {
        float4 v;
        v.x = fmaf(xr[kk[0]], w4[0], a4[0]);
        v.y = fmaf(xr[kk[1]], w4[1], a4[1]);
        v.z = fmaf(xr[kk[2]], w4[2], a4[2]);
        v.w = fmaf(xr[kk[3]], w4[3], a4[3]);
        *op = v;
        xr += 128 * K;                                        // m advances by 128
        op += (size_t)(GRID * 2) * F4_PER_PAIR;               // p advances by 4096
    }
}

extern "C" void kernel_launch(void* const* d_in, const int* in_sizes, int n_in,
                              void* d_out, int out_size, void* d_ws, size_t ws_size,
                              hipStream_t stream) {
    const float* x       = (const float*)d_in[0];
    const float* w_bet   = (const float*)d_in[1];
    const float* b_bet   = (const float*)d_in[2];
    const float* w_stack = (const float*)d_in[3];
    const float* b_stack = (const float*)d_in[4];
    const float* w_call  = (const float*)d_in[5];
    const float* b_call  = (const float*)d_in[6];
    const float* w_odds  = (const float*)d_in[7];
    const float* b_odds  = (const float*)d_in[8];
    const float* oe      = (const float*)d_in[9];
    float* out = (float*)d_out;

    fuse_scramble_kernel<<<GRID, BLOCK, 0, stream>>>(
        x, w_bet, b_bet, w_stack, b_stack, w_call, b_call, w_odds, b_odds, oe, out);
}